// Round 14
// baseline (371.959 us; speedup 1.0000x reference)
//
#include <hip/hip_runtime.h>
#include <hip/hip_bf16.h>

#define N_ 50000
#define E_ 800000
#define IN_ 128
#define OUT_ 128
#define ASSIGN_ 256
#define B_ 32
#define KTOT 256     // 2*IN
#define JTOT 384     // OUT + ASSIGN
#define HCHUNK 32
#define ACHUNK 32
#define AST 72       // k_adjm LDS row stride in u16
#define NXP ((N_ + 127) / 128)       // 391 row panels
#define NGB (NXP * 3)                // 1173 gemm blocks
#define NCVX 6250                    // (N*128/4)/256 exact
#define NAGU 12500                   // agg units (4 nodes each); N = 4*NAGU exactly
#define NAG 4096                     // fused agg|gemm grid

// edge bucket sort: 256 buckets (full CU coverage in k_binB)
#define NBKT 256
#define NPB 196      // ceil(N/NBKT): bucket b owns nodes [196b, 196b+196)
#define BCAP 4000    // mean 3125 + 15.6 sigma
#define EPB 4096
#define NBLK_A ((E_ + EPB - 1) / EPB)  // 196
#define NPRE (NBLK_A + NCVX + 384)     // fused pre kernel grid

typedef __attribute__((ext_vector_type(8))) short short8;
typedef __attribute__((ext_vector_type(4))) float f32x4;
typedef __attribute__((ext_vector_type(2))) float f32x2;
typedef __attribute__((ext_vector_type(4))) unsigned short ushort4v;
typedef __attribute__((ext_vector_type(2))) unsigned short ushort2v;
typedef unsigned short u16;
typedef unsigned long long u64;

__device__ inline unsigned short f2bf(float v) {
    union { float f; unsigned u; } a;
    a.f = v;
    unsigned r = a.u + 0x7fff + ((a.u >> 16) & 1);  // RNE
    return (unsigned short)(r >> 16);
}
__device__ inline float bf2f(unsigned short b) {
    union { unsigned u; float f; } a;
    a.u = ((unsigned)b) << 16;
    return a.f;
}

// ---- fp8 e4m3 encode (RNE via f32 bit trick; |v| < 448 assumed) ----
__device__ inline unsigned enc8(float v) {
    union { float f; unsigned u; } a;
    a.f = v * 0x1p-120f;
    unsigned b = a.u;
    unsigned r = b + 0x7FFFF + ((b >> 20) & 1);
    return ((r >> 20) & 0x7F) | ((b >> 24) & 0x80);
}
// ---- fp8 e4m3 pair decode ----
__device__ inline float2 dec8x2(unsigned short p) {
#if defined(__has_builtin) && __has_builtin(__builtin_amdgcn_cvt_pk_f32_fp8)
    f32x2 r = __builtin_amdgcn_cvt_pk_f32_fp8((int)(unsigned)p, false);
    return make_float2(r.x, r.y);
#else
    unsigned u0 = p & 0xffu, u1 = (p >> 8) & 0xffu;
    union { unsigned u; float f; } a, b;
    a.u = ((u0 & 0x80u) << 24) | ((u0 & 0x7fu) << 20);
    b.u = ((u1 & 0x80u) << 24) | ((u1 & 0x7fu) << 20);
    return make_float2(a.f * 0x1p+120f, b.f * 0x1p+120f);
#endif
}

// ---- async global->LDS, 16B per lane; dest = wave-uniform base + lane*16 ----
__device__ __forceinline__ void gload16(const u16* g, u16* l) {
    __builtin_amdgcn_global_load_lds(
        (const __attribute__((address_space(1))) void*)g,
        (__attribute__((address_space(3))) void*)l, 16, 0, 0);
}

// ---------------- fused pre: binA | x-convert | W prep ----------------
__global__ __launch_bounds__(256) void k_pre(const int* __restrict__ ei,
                                             int* __restrict__ bktFill,
                                             int2* __restrict__ ebkt,
                                             const float* __restrict__ x,
                                             unsigned short* __restrict__ xhi,
                                             unsigned char* __restrict__ xq,
                                             const float* __restrict__ We,
                                             const float* __restrict__ be,
                                             const float* __restrict__ Wp,
                                             const float* __restrict__ bp,
                                             unsigned short* __restrict__ WThi,
                                             float* __restrict__ bias) {
    __shared__ int lh[NBKT], lbase[NBKT], lofs[NBKT];
    int bid = blockIdx.x;
    int t = threadIdx.x;
    if (bid < NBLK_A) {
        int e0 = bid * EPB;
        lh[t] = 0; lofs[t] = 0;
        __syncthreads();
        int ss[16], dd[16];
#pragma unroll
        for (int i = 0; i < 16; i++) {
            int e = e0 + i * 256 + t;
            ss[i] = 0; dd[i] = -1;
            if (e < E_) {
                ss[i] = ei[e];
                dd[i] = ei[E_ + e];
                atomicAdd(&lh[dd[i] / NPB], 1);
            }
        }
        __syncthreads();
        lbase[t] = t * BCAP + atomicAdd(&bktFill[t], lh[t]);
        __syncthreads();
#pragma unroll
        for (int i = 0; i < 16; i++) {
            if (dd[i] >= 0) {
                int b = dd[i] / NPB;
                int o = atomicAdd(&lofs[b], 1);
                ebkt[lbase[b] + o] = make_int2(ss[i], dd[i]);
            }
        }
        return;
    }
    if (bid >= NBLK_A + NCVX) {  // prep tail
        int idx = (bid - NBLK_A - NCVX) * 256 + t;
        if (idx < JTOT * KTOT) {
            int j = idx / KTOT, k = idx - j * KTOT;
            float v = (j < 128) ? We[k * 128 + j] : Wp[k * 256 + (j - 128)];
            WThi[idx] = f2bf(v);
        }
        if (idx < JTOT) bias[idx] = (idx < 128) ? be[idx] : bp[idx - 128];
        return;
    }
    int i4 = ((bid - NBLK_A) * 256 + t) * 4;
    if (i4 >= N_ * 128) return;
    float4 v = *(const float4*)(x + i4);
    ushort4v h;
    h.x = f2bf(v.x); h.y = f2bf(v.y); h.z = f2bf(v.z); h.w = f2bf(v.w);
    *(ushort4v*)(xhi + i4) = h;
    unsigned q = enc8(v.x) | (enc8(v.y) << 8) | (enc8(v.z) << 16) | (enc8(v.w) << 24);
    *(unsigned*)(xq + i4) = q;
}

// ---------------- fused B: histogram + scan + publish/wait handshake + CSR scatter ----
// 256 blocks (one per bucket, full CU coverage). Atomic-only cross-block comms;
// NO __threadfence (round-6 lesson: per-block device fences = L2 writeback storm).
__global__ __launch_bounds__(256) void k_binB(const int* __restrict__ bktFill,
                                              const int2* __restrict__ ebkt,
                                              int* __restrict__ ready,
                                              int* __restrict__ rowStart,
                                              int* __restrict__ csr_src,
                                              int* __restrict__ csr_dst) {
    __shared__ int ldeg[NPB];
    __shared__ int lscan[256];
    __shared__ int bsc[NBKT];
    __shared__ int lfill[NPB];
    int b = blockIdx.x, t = threadIdx.x;
    if (t < NPB) ldeg[t] = 0;
    __syncthreads();
    int base = b * BCAP;
    int cnt = bktFill[b];
    int n0 = b * NPB;
    for (int j = t; j < cnt; j += 256)
        atomicAdd(&ldeg[ebkt[base + j].y - n0], 1);
    __syncthreads();
    lscan[t] = (t < NPB) ? ldeg[t] : 0;
    __syncthreads();
    for (int off = 1; off < 256; off <<= 1) {
        int x0 = lscan[t];
        int a0 = (t >= off) ? lscan[t - off] : 0;
        __syncthreads();
        lscan[t] = x0 + a0;
        __syncthreads();
    }
    // publish own total, then wait for all (publish-before-wait, grid <= CU count)
    if (t == 0) atomicExch(&ready[b], lscan[NPB - 1] + 1);
    {
        int v;
        while ((v = atomicAdd(&ready[t], 0)) == 0) __builtin_amdgcn_s_sleep(8);
        bsc[t] = v - 1;
    }
    __syncthreads();
    for (int off = 1; off < NBKT; off <<= 1) {
        int x = bsc[t];
        int add = (t >= off) ? bsc[t - off] : 0;
        __syncthreads();
        bsc[t] = x + add;
        __syncthreads();
    }
    int base0 = (b == 0) ? 0 : bsc[b - 1];
    if (t < NPB) {
        int n = n0 + t;
        if (n < N_) {
            int excl = (t == 0) ? 0 : lscan[t - 1];
            lfill[t] = excl;
            rowStart[n] = base0 + excl;
        }
    }
    __syncthreads();
    for (int j = t; j < cnt; j += 256) {
        int2 sd = ebkt[base + j];
        int p = base0 + atomicAdd(&lfill[sd.y - n0], 1);
        csr_src[p] = sd.x;
        csr_dst[p] = sd.y;
    }
    if (b == 0 && t == 0) rowStart[N_] = E_;
}

// ---------------- fused agg|gemm: work-stealing agg queue, then GEMM ----------------
// EVERY block first drains the agg unit queue (unit = 4 nodes, full residency =>
// the L2 line-wall runs at max parallelism, round-11 lesson). Deadlock-free by
// construction: a block only waits AFTER the queue is empty, i.e. every unit is
// claimed by an already-dispatched block => all panel flags eventually set,
// regardless of dispatch order. nhi publish = agent-scope atomic stores +
// __syncthreads (vmcnt drain) + panel counter (round-10-validated; NO fences).
#define LDA 40
__global__ __launch_bounds__(256) void k_ag(const unsigned char* __restrict__ xq,
                                            const int* __restrict__ rowStart,
                                            const int* __restrict__ csr_src,
                                            unsigned short* nhi,
                                            const unsigned short* __restrict__ xhi,
                                            const unsigned short* __restrict__ WThi,
                                            const float* __restrict__ bias,
                                            unsigned short* __restrict__ embed,
                                            unsigned short* __restrict__ plog,
                                            int* __restrict__ aggCtr,
                                            int* __restrict__ panelCnt) {
    __shared__ __align__(16) union {
        struct { u16 A[2][128 * 32]; u16 B[2][128 * 32]; } s;   // 32 KB dbuf
        u16 ep[64 * 128];  // 16 KB epilogue tile
    } sm;
    __shared__ int unitSh;
    int t = threadIdx.x;
    int wave = t >> 6, lane = t & 63;
    int wm = wave >> 1, wn = wave & 1;
    int q = lane >> 4, lr = lane & 15;
    int id = blockIdx.x;

    // ---- phase 1: drain agg queue (all blocks) ----
    {
        int es = lane >> 3;
        int fb = lane & 7;
        for (;;) {
            __syncthreads();
            if (t == 0) unitSh = atomicAdd(aggCtr, 1);
            __syncthreads();
            int u = unitSh;
            if (u >= NAGU) break;
            int node = u * 4 + wave;           // N = 4*NAGU: always valid
            int a = rowStart[node], bnd = rowStart[node + 1];
            float aacc[16];
#pragma unroll
            for (int k = 0; k < 16; k++) aacc[k] = 0.f;
#define DEC(Q)                                                       \
            {                                                        \
                unsigned wq[4] = {(Q).x, (Q).y, (Q).z, (Q).w};       \
                _Pragma("unroll")                                    \
                for (int wi = 0; wi < 4; wi++) {                     \
                    float2 f01 = dec8x2((unsigned short)(wq[wi] & 0xffffu)); \
                    float2 f23 = dec8x2((unsigned short)(wq[wi] >> 16));     \
                    aacc[wi * 4 + 0] += f01.x; aacc[wi * 4 + 1] += f01.y;    \
                    aacc[wi * 4 + 2] += f23.x; aacc[wi * 4 + 3] += f23.y;    \
                }                                                    \
            }
            int j = a;
            for (; j + 8 < bnd; j += 16) {
                int s0 = csr_src[j + es];
                uint4 q0 = *(const uint4*)(xq + (size_t)s0 * 128 + fb * 16);
                uint4 q1 = {0, 0, 0, 0};
                int e1 = j + 8 + es;
                if (e1 < bnd) {
                    int s1 = csr_src[e1];
                    q1 = *(const uint4*)(xq + (size_t)s1 * 128 + fb * 16);
                }
                DEC(q0);
                DEC(q1);
            }
            if (j < bnd) {
                uint4 q0 = {0, 0, 0, 0};
                int e0 = j + es;
                if (e0 < bnd) {
                    int s0 = csr_src[e0];
                    q0 = *(const uint4*)(xq + (size_t)s0 * 128 + fb * 16);
                }
                DEC(q0);
            }
#undef DEC
#pragma unroll
            for (int k = 0; k < 16; k++) {
                aacc[k] += __shfl_xor(aacc[k], 8, 64);
                aacc[k] += __shfl_xor(aacc[k], 16, 64);
                aacc[k] += __shfl_xor(aacc[k], 32, 64);
            }
            float inv = 1.0f / (float)max(bnd - a, 1);
            if (es == 0) {
                u64* dst = (u64*)(nhi + (size_t)node * 128 + fb * 16);
#pragma unroll
                for (int kk = 0; kk < 4; kk++) {
                    u64 wv = (u64)f2bf(aacc[4 * kk + 0] * inv)
                           | ((u64)f2bf(aacc[4 * kk + 1] * inv) << 16)
                           | ((u64)f2bf(aacc[4 * kk + 2] * inv) << 32)
                           | ((u64)f2bf(aacc[4 * kk + 3] * inv) << 48);
                    __hip_atomic_store(dst + kk, wv, __ATOMIC_RELAXED, __HIP_MEMORY_SCOPE_AGENT);
                }
            }
            __syncthreads();   // drains vmcnt: all 4 nodes' stores at coherent point
            if (t == 0) atomicAdd(&panelCnt[u >> 5], 1);
        }
    }
    if (id >= NGB) return;

    // ---- phase 2: GEMM (blocks 0..NGB-1) ----
    int xi, cc;
    if (id < (NXP / 8) * 24) {           // 1152
        xi = (id / 24) * 8 + (id & 7);
        cc = (id % 24) >> 3;
    } else {
        int r2 = id - (NXP / 8) * 24;    // 0..20 over 7 tail panels
        xi = (NXP / 8) * 8 + r2 % (NXP % 8);
        cc = r2 / (NXP % 8);
    }
    int row0 = xi * 128;
    int col0 = cc * 128;
    int target = min(32, (N_ - row0 + 3) >> 2);   // units in my panel

    f32x4 acc[4][4] = {};

    // per-lane DMA geometry: 2 A-segments + 2 B-segments per wave per K-step
    int segRow[2], segSl[2];
#pragma unroll
    for (int i = 0; i < 2; i++) {
        int R0 = (wave * 2 + i) * 16;
        segRow[i] = R0 + (lane >> 2);
        segSl[i] = (lane & 3) ^ ((segRow[i] >> 1) & 3);
    }

#define ISSUE(KT, BUF)                                                               \
    {                                                                                \
        const u16* Asrc = ((KT) < 128) ? xhi : (const u16*)nhi;                      \
        int kb = (KT) & 127;                                                         \
        _Pragma("unroll")                                                            \
        for (int i = 0; i < 2; i++) {                                                \
            int nd = row0 + segRow[i];                                               \
            if (nd >= N_) nd = N_ - 1;                                               \
            gload16(Asrc + (size_t)nd * 128 + kb + segSl[i] * 8,                     \
                    &sm.s.A[BUF][((wave * 2 + i) * 16) * 32] + lane * 8);            \
            gload16(WThi + (size_t)(col0 + segRow[i]) * 256 + (KT) + segSl[i] * 8,   \
                    &sm.s.B[BUF][((wave * 2 + i) * 16) * 32] + lane * 8);            \
        }                                                                            \
    }

    ISSUE(0, 0);
    int p = 0;
    for (int kt = 0; kt < KTOT; kt += 32, p ^= 1) {
        __syncthreads();                       // vmcnt(0)+barrier: buf p ready
        if (kt + 32 < KTOT) {
            if (kt + 32 == 128) {              // my panel's nhi must be published
                if (t == 0) {
                    while (atomicAdd(&panelCnt[xi], 0) < target) __builtin_amdgcn_s_sleep(16);
                }
                __syncthreads();
            }
            ISSUE(kt + 32, p ^ 1);
        }

        short8 afh[4];
#pragma unroll
        for (int mi = 0; mi < 4; mi++) {
            int r = wm * 64 + mi * 16 + lr;
            afh[mi] = *(const short8*)&sm.s.A[p][r * 32 + ((q * 8) ^ (((r >> 1) & 3) * 8))];
        }
#pragma unroll
        for (int ni = 0; ni < 4; ni++) {
            int r = wn * 64 + ni * 16 + lr;
            short8 bfh = *(const short8*)&sm.s.B[p][r * 32 + ((q * 8) ^ (((r >> 1) & 3) * 8))];
#pragma unroll
            for (int mi = 0; mi < 4; mi++)
                acc[mi][ni] = __builtin_amdgcn_mfma_f32_16x16x32_bf16(afh[mi], bfh, acc[mi][ni], 0, 0, 0);
        }
    }
#undef ISSUE

    // epilogue: two 64-row halves through LDS, full-line coalesced stores
    for (int half = 0; half < 2; half++) {
        __syncthreads();
        if (wm == half) {
#pragma unroll
            for (int mi = 0; mi < 4; mi++)
#pragma unroll
                for (int ni = 0; ni < 4; ni++) {
                    int lcol = wn * 64 + ni * 16 + lr;
                    float bj = bias[col0 + lcol];
#pragma unroll
                    for (int r = 0; r < 4; r++) {
                        int lrow = mi * 16 + q * 4 + r;
                        sm.ep[lrow * 128 + lcol] = f2bf(acc[mi][ni][r] + bj);
                    }
                }
        }
        __syncthreads();
#pragma unroll
        for (int i = 0; i < 4; i++) {
            int chunk = i * 256 + t;          // 0..1023
            int lrow = chunk >> 4;            // 64 rows x 16 chunks
            int lco = (chunk & 15) * 8;       // u16 offset
            int grow = row0 + half * 64 + lrow;
            if (grow < N_) {
                short8 v = *(const short8*)&sm.ep[lrow * 128 + lco];
                if (col0 < 128)
                    *(short8*)(embed + (size_t)grow * 128 + lco) = v;
                else
                    *(short8*)(plog + (size_t)grow * 256 + (col0 - 128) + lco) = v;
            }
        }
    }
}

// ---------------- double softmax -> compact r8[N][8] (fp32 + bf16 copy) ----------------
__global__ __launch_bounds__(256) void k_r(const unsigned short* __restrict__ plog,
                                           const int* __restrict__ batch,
                                           float* __restrict__ r8,
                                           unsigned short* __restrict__ r8b) {
    int node = blockIdx.x * 4 + (threadIdx.x >> 6);
    int lane = threadIdx.x & 63;
    if (node >= N_) return;
    ushort4v p4 = *(const ushort4v*)(plog + (size_t)node * 256 + lane * 4);
    float px = bf2f(p4.x), py = bf2f(p4.y), pz = bf2f(p4.z), pw = bf2f(p4.w);
    float m = fmaxf(fmaxf(px, py), fmaxf(pz, pw));
    for (int off = 32; off; off >>= 1) m = fmaxf(m, __shfl_xor(m, off, 64));
    float s = expf(px - m) + expf(py - m) + expf(pz - m) + expf(pw - m);
    for (int off = 32; off; off >>= 1) s += __shfl_xor(s, off, 64);
    int g = batch[node];
    float v = 0.f;
    if (lane < 8) v = expf(bf2f(plog[(size_t)node * 256 + g * 8 + lane]) - m) / s;
    float M2 = v;
    for (int off = 4; off; off >>= 1) M2 = fmaxf(M2, __shfl_xor(M2, off, 64));
    float e = expf(v - M2);
    float Sg = e;
    for (int off = 4; off; off >>= 1) Sg += __shfl_xor(Sg, off, 64);
    float D2 = Sg + 248.0f * expf(-M2);
    float r = e / (Sg + 1e-13f * D2);
    if (lane < 8) {
        r8[node * 8 + lane] = r;
        r8b[node * 8 + lane] = f2bf(r);
    }
}

// ---------------- fused tail: adjm (ids < 1024) | h_part (ids >= 1024) ----------------
// adjm: 2 barriers/tile (zero-prev merged into write phase) + register prefetch.
// h_part: embed read ONCE (short2/lane), 4-wave LDS reduce reusing Ab's storage.
__global__ __launch_bounds__(256) void k_tail(const int* __restrict__ rowStart,
                                              const int* __restrict__ csr_src,
                                              const int* __restrict__ csr_dst,
                                              const unsigned short* __restrict__ r8b,
                                              float* __restrict__ partAdj,
                                              const unsigned short* __restrict__ embed,
                                              const float* __restrict__ r8,
                                              float* __restrict__ partH) {
    __shared__ __align__(16) unsigned short Ab[256 * AST];  // [col=gs*8+a][e]; h_part: hred
    __shared__ __align__(16) unsigned short Bb[16 * AST];   // [n=b][e]
    int id = blockIdx.x;
    int t = threadIdx.x;
    if (id >= B_ * ACHUNK) {
        // ---- h_part ----
        int idh = id - B_ * ACHUNK;
        int g = idh & 31;
        int c = idh >> 5;
        int wv = t >> 6, l = t & 63;
        int n0g = (g * N_ + 31) >> 5;
        int n1g = ((g + 1) * N_ + 31) >> 5;
        int len = n1g - n0g;
        int a = n0g + (len * c) / HCHUNK;
        int b = n0g + (len * (c + 1)) / HCHUNK;
        float acc[8][2] = {};
        for (int n = a + wv; n < b; n += 4) {
            unsigned e2 = *(const unsigned*)(embed + (size_t)n * 128 + l * 2);
            float e0 = bf2f((u16)(e2 & 0xffffu));
            float e1 = bf2f((u16)(e2 >> 16));
            f32x4 r0 = *(const f32x4*)(r8 + n * 8);       // broadcast (same addr all lanes)
            f32x4 r1 = *(const f32x4*)(r8 + n * 8 + 4);
#pragma unroll
            for (int c2 = 0; c2 < 4; c2++) {
                acc[c2][0] += r0[c2] * e0; acc[c2][1] += r0[c2] * e1;
                acc[c2 + 4][0] += r1[c2] * e0; acc[c2 + 4][1] += r1[c2] * e1;
            }
        }
        float* hredf = (float*)Ab;   // 16 KB of Ab's 36.9 KB
#pragma unroll
        for (int c2 = 0; c2 < 8; c2++) {
            hredf[wv * 1024 + c2 * 128 + l * 2] = acc[c2][0];
            hredf[wv * 1024 + c2 * 128 + l * 2 + 1] = acc[c2][1];
        }
        __syncthreads();
        float* pb = partH + (g * HCHUNK + c) * 1024;
        for (int o = t; o < 1024; o += 256)
            pb[o] = (hredf[o] + hredf[1024 + o]) + (hredf[2048 + o] + hredf[3072 + o]);
        return;
    }
    // ---- adjm ----
    int gd = id & 31;
    int c = id >> 5;
    int wave = t >> 6, lane = t & 63;
    int q = lane >> 4, lr = lane & 15;
    int n0g = (gd * N_ + 31) >> 5;
    int n1g = ((gd + 1) * N_ + 31) >> 5;
    int len = n1g - n0g;
    int na = n0g + (len * c) / ACHUNK;
    int nb = n0g + (len * (c + 1)) / ACHUNK;
    int j0 = rowStart[na], j1 = rowStart[nb];

    uint4 z = {0, 0, 0, 0};
#pragma unroll
    for (int i = 0; i < 9; i++) *(uint4*)&Ab[(i * 256 + t) * 8] = z;
    if (t < 144) *(uint4*)&Bb[t * 8] = z;
    __syncthreads();

    f32x4 acc[4] = {};
    int el = t >> 2;
    int ap = t & 3;

    int jcur = j0 + el;
    unsigned sv = 0, dv = 0;
    int gs = 0;
    bool have = jcur < j1;
    if (have) {
        int s = csr_src[jcur];
        int d = csr_dst[jcur];
        gs = (s * B_) / N_;
        sv = *(const unsigned*)(r8b + (size_t)s * 8 + ap * 2);
        dv = *(const unsigned*)(r8b + (size_t)d * 8 + ap * 2);
    }
    int pca = -1;

    for (int jt = j0; jt < j1; jt += 64) {
        if (pca >= 0) {
            Ab[pca * AST + el] = 0;
            Ab[(pca + 1) * AST + el] = 0;
            Bb[(ap * 2) * AST + el] = 0;
            Bb[(ap * 2 + 1) * AST + el] = 0;
        }
        int ca = -1;
        if (have) {
            ca = gs * 8 + ap * 2;
            Ab[ca * AST + el] = (unsigned short)sv;
            Ab[(ca + 1) * AST + el] = (unsigned short)(sv >> 16);
            Bb[(ap * 2) * AST + el] = (unsigned short)dv;
            Bb[(ap * 2 + 1) * AST + el] = (unsigned short)(dv >> 16);
        }
        __syncthreads();
        int jn = jt + 64 + el;
        bool haveN = jn < j1;
        unsigned svN = 0, dvN = 0;
        int gsN = 0;
        if (haveN) {
            int s = csr_src[jn];
            int d = csr_dst[jn];
            gsN = (s * B_) / N_;
            svN = *(const unsigned*)(r8b + (size_t)s * 8 + ap * 2);
            dvN = *(const unsigned*)(r8b + (size_t)d * 8 + ap * 2);
        }
        short8 bf0 = *(const short8*)&Bb[lr * AST + q * 8];
        short8 bf1 = *(const short8*)&Bb[lr * AST + 32 + q * 8];
#pragma unroll
        for (int mi = 0; mi < 4; mi++) {
            int col = (wave * 4 + mi) * 16 + lr;
            short8 a0 = *(const short8*)&Ab[col * AST + q * 8];
            short8 a1 = *(const short8*)&Ab[col * AST + 32 + q * 8];
            acc[mi] = __builtin_amdgcn_mfma_f32_16x16x32_bf16(a0, bf0, acc[mi], 0, 0, 0);
            acc[mi] = __builtin_amdgcn_mfma_f32_16x16x32_bf16(a1, bf1, acc[mi], 0, 0, 0);
        }
        __syncthreads();
        pca = ca;
        have = haveN; gs = gsN; sv = svN; dv = dvN;
    }

    float* pb = partAdj + (gd * ACHUNK + c) * 2048;
    if (lr < 8) {
#pragma unroll
        for (int mi = 0; mi < 4; mi++) {
            int mbase = (wave * 4 + mi) * 16 + q * 4;
#pragma unroll
            for (int r = 0; r < 4; r++)
                pb[(mbase + r) * 8 + lr] = acc[mi][r];
        }
    }
}

// ---------------- fused adj + h reduce ----------------
__global__ __launch_bounds__(256) void k_red(const float* __restrict__ partAdj,
                                             const float* __restrict__ partH,
                                             float* __restrict__ out) {
    int o = blockIdx.x * 256 + threadIdx.x;
    if (o < 256 * 256) {
        int row = o >> 8, col = o & 255;
        int gd = col >> 3, b = col & 7;
        int li = row * 8 + b;
        float s = 0.f;
#pragma unroll
        for (int c = 0; c < ACHUNK; c++) s += partAdj[(gd * ACHUNK + c) * 2048 + li];
        out[o] = s;
    } else {
        int idx = o - 256 * 256;            // < 32768 by grid sizing
        int g = idx >> 10;
        int local = idx & 1023;
        float s = 0.f;
#pragma unroll
        for (int c = 0; c < HCHUNK; c++) s += partH[(g * HCHUNK + c) * 1024 + local];
        out[256 * 256 + idx] = s;
    }
}

extern "C" void kernel_launch(void* const* d_in, const int* in_sizes, int n_in,
                              void* d_out, int out_size, void* d_ws, size_t ws_size,
                              hipStream_t stream) {
    const float* x = (const float*)d_in[0];
    const int* ei = (const int*)d_in[1];
    const int* batch = (const int*)d_in[2];
    const float* We = (const float*)d_in[3];
    const float* be = (const float*)d_in[4];
    const float* Wp = (const float*)d_in[5];
    const float* bp = (const float*)d_in[6];
    float* out = (float*)d_out;  // [adj 256*256 | h 256*128]

    char* w = (char*)d_ws;
    auto alloc = [&](size_t bytes) -> char* {
        char* p = w;
        w += (bytes + 255) & ~(size_t)255;
        return p;
    };
    unsigned short* xhi = (unsigned short*)alloc((size_t)N_ * 128 * 2);
    unsigned char* xq = (unsigned char*)alloc((size_t)N_ * 128);
    unsigned short* nhi = (unsigned short*)alloc((size_t)N_ * 128 * 2);
    unsigned short* WThi = (unsigned short*)alloc((size_t)JTOT * KTOT * 2);
    unsigned short* embed = (unsigned short*)alloc((size_t)N_ * 128 * 2);
    unsigned short* plog = (unsigned short*)alloc((size_t)N_ * 256 * 2);
    float* r8 = (float*)alloc((size_t)N_ * 8 * 4);
    unsigned short* r8b = (unsigned short*)alloc((size_t)N_ * 8 * 2);
    float* bias = (float*)alloc(JTOT * 4);
    int* rowStart = (int*)alloc((size_t)(N_ + 1) * 4);
    int* csr_src = (int*)alloc((size_t)E_ * 4);
    int* csr_dst = (int*)alloc((size_t)E_ * 4);
    int* flags = (int*)alloc((2 * NBKT + 8 + NXP) * 4);  // [bktFill | ready | aggCtr(pad8) | panelCnt]
    int* bktFill = flags;
    int* ready = flags + NBKT;
    int* aggCtr = flags + 2 * NBKT;
    int* panelCnt = flags + 2 * NBKT + 8;
    int2* ebkt = (int2*)alloc((size_t)NBKT * BCAP * 8);
    float* partH = (float*)alloc((size_t)B_ * HCHUNK * 1024 * 4);
    float* partAdj = (float*)alloc((size_t)B_ * ACHUNK * 2048 * 4);

    hipMemsetAsync(flags, 0, (2 * NBKT + 8 + NXP) * 4, stream);
    k_pre<<<NPRE, 256, 0, stream>>>(ei, bktFill, ebkt, x, xhi, xq, We, be, Wp, bp, WThi, bias);
    k_binB<<<NBKT, 256, 0, stream>>>(bktFill, ebkt, ready, rowStart, csr_src, csr_dst);
    k_ag<<<NAG, 256, 0, stream>>>(xq, rowStart, csr_src, nhi, xhi, WThi, bias, embed, plog,
                                  aggCtr, panelCnt);
    k_r<<<(N_ + 3) / 4, 256, 0, stream>>>(plog, batch, r8, r8b);
    k_tail<<<2 * B_ * ACHUNK, 256, 0, stream>>>(rowStart, csr_src, csr_dst, r8b, partAdj,
                                                embed, r8, partH);
    k_red<<<(256 * 256 + 256 * 128 + 255) / 256, 256, 0, stream>>>(partAdj, partH, out);
}

// Round 15
// 212.796 us; speedup vs baseline: 1.7480x; 1.7480x over previous
//
#include <hip/hip_runtime.h>
#include <hip/hip_bf16.h>

#define N_ 50000
#define E_ 800000
#define IN_ 128
#define OUT_ 128
#define ASSIGN_ 256
#define B_ 32
#define KTOT 256     // 2*IN
#define JTOT 384     // OUT + ASSIGN
#define HCHUNK 32
#define ACHUNK 32
#define AST 72       // k_adjm LDS row stride in u16
#define NXP ((N_ + 127) / 128)       // 391 row panels
#define NGB (NXP * 3)                // 1173 gemm blocks
#define NCVX 6250                    // (N*128/4)/256 exact

// edge bucket sort: 256 buckets (full CU coverage in k_binB)
#define NBKT 256
#define NPB 196      // ceil(N/NBKT): bucket b owns nodes [196b, 196b+196)
#define BCAP 4000    // mean 3125 + 15.6 sigma
#define EPB 4096
#define NBLK_A ((E_ + EPB - 1) / EPB)  // 196
#define NPRE (NBLK_A + NCVX + 384)     // fused pre kernel grid

typedef __attribute__((ext_vector_type(8))) short short8;
typedef __attribute__((ext_vector_type(4))) float f32x4;
typedef __attribute__((ext_vector_type(2))) float f32x2;
typedef __attribute__((ext_vector_type(4))) unsigned short ushort4v;
typedef __attribute__((ext_vector_type(2))) unsigned short ushort2v;
typedef unsigned short u16;

__device__ inline unsigned short f2bf(float v) {
    union { float f; unsigned u; } a;
    a.f = v;
    unsigned r = a.u + 0x7fff + ((a.u >> 16) & 1);  // RNE
    return (unsigned short)(r >> 16);
}
__device__ inline float bf2f(unsigned short b) {
    union { unsigned u; float f; } a;
    a.u = ((unsigned)b) << 16;
    return a.f;
}

// ---- fp8 e4m3 encode (RNE via f32 bit trick; |v| < 448 assumed) ----
__device__ inline unsigned enc8(float v) {
    union { float f; unsigned u; } a;
    a.f = v * 0x1p-120f;
    unsigned b = a.u;
    unsigned r = b + 0x7FFFF + ((b >> 20) & 1);
    return ((r >> 20) & 0x7F) | ((b >> 24) & 0x80);
}
// ---- fp8 e4m3 pair decode ----
__device__ inline float2 dec8x2(unsigned short p) {
#if defined(__has_builtin) && __has_builtin(__builtin_amdgcn_cvt_pk_f32_fp8)
    f32x2 r = __builtin_amdgcn_cvt_pk_f32_fp8((int)(unsigned)p, false);
    return make_float2(r.x, r.y);
#else
    unsigned u0 = p & 0xffu, u1 = (p >> 8) & 0xffu;
    union { unsigned u; float f; } a, b;
    a.u = ((u0 & 0x80u) << 24) | ((u0 & 0x7fu) << 20);
    b.u = ((u1 & 0x80u) << 24) | ((u1 & 0x7fu) << 20);
    return make_float2(a.f * 0x1p+120f, b.f * 0x1p+120f);
#endif
}

// ---- async global->LDS, 16B per lane; dest = wave-uniform base + lane*16 ----
__device__ __forceinline__ void gload16(const u16* g, u16* l) {
    __builtin_amdgcn_global_load_lds(
        (const __attribute__((address_space(1))) void*)g,
        (__attribute__((address_space(3))) void*)l, 16, 0, 0);
}

// ---------------- fused pre: binA | x-convert | W prep ----------------
__global__ __launch_bounds__(256) void k_pre(const int* __restrict__ ei,
                                             int* __restrict__ bktFill,
                                             int2* __restrict__ ebkt,
                                             const float* __restrict__ x,
                                             unsigned short* __restrict__ xhi,
                                             unsigned char* __restrict__ xq,
                                             const float* __restrict__ We,
                                             const float* __restrict__ be,
                                             const float* __restrict__ Wp,
                                             const float* __restrict__ bp,
                                             unsigned short* __restrict__ WThi,
                                             float* __restrict__ bias) {
    __shared__ int lh[NBKT], lbase[NBKT], lofs[NBKT];
    int bid = blockIdx.x;
    int t = threadIdx.x;
    if (bid < NBLK_A) {
        int e0 = bid * EPB;
        lh[t] = 0; lofs[t] = 0;
        __syncthreads();
        int ss[16], dd[16];
#pragma unroll
        for (int i = 0; i < 16; i++) {
            int e = e0 + i * 256 + t;
            ss[i] = 0; dd[i] = -1;
            if (e < E_) {
                ss[i] = ei[e];
                dd[i] = ei[E_ + e];
                atomicAdd(&lh[dd[i] / NPB], 1);
            }
        }
        __syncthreads();
        lbase[t] = t * BCAP + atomicAdd(&bktFill[t], lh[t]);
        __syncthreads();
#pragma unroll
        for (int i = 0; i < 16; i++) {
            if (dd[i] >= 0) {
                int b = dd[i] / NPB;
                int o = atomicAdd(&lofs[b], 1);
                ebkt[lbase[b] + o] = make_int2(ss[i], dd[i]);
            }
        }
        return;
    }
    if (bid >= NBLK_A + NCVX) {  // prep tail
        int idx = (bid - NBLK_A - NCVX) * 256 + t;
        if (idx < JTOT * KTOT) {
            int j = idx / KTOT, k = idx - j * KTOT;
            float v = (j < 128) ? We[k * 128 + j] : Wp[k * 256 + (j - 128)];
            WThi[idx] = f2bf(v);
        }
        if (idx < JTOT) bias[idx] = (idx < 128) ? be[idx] : bp[idx - 128];
        return;
    }
    int i4 = ((bid - NBLK_A) * 256 + t) * 4;
    if (i4 >= N_ * 128) return;
    float4 v = *(const float4*)(x + i4);
    ushort4v h;
    h.x = f2bf(v.x); h.y = f2bf(v.y); h.z = f2bf(v.z); h.w = f2bf(v.w);
    *(ushort4v*)(xhi + i4) = h;
    unsigned q = enc8(v.x) | (enc8(v.y) << 8) | (enc8(v.z) << 16) | (enc8(v.w) << 24);
    *(unsigned*)(xq + i4) = q;
}

// ---------------- fused B: histogram + scan + publish/wait handshake + CSR scatter ----
// 256 blocks (one per bucket, full CU coverage). Atomic-only cross-block comms;
// NO __threadfence (round-6 lesson: per-block device fences = L2 writeback storm).
__global__ __launch_bounds__(256) void k_binB(const int* __restrict__ bktFill,
                                              const int2* __restrict__ ebkt,
                                              int* __restrict__ ready,
                                              int* __restrict__ rowStart,
                                              int* __restrict__ csr_src,
                                              int* __restrict__ csr_dst) {
    __shared__ int ldeg[NPB];
    __shared__ int lscan[256];
    __shared__ int bsc[NBKT];
    __shared__ int lfill[NPB];
    int b = blockIdx.x, t = threadIdx.x;
    if (t < NPB) ldeg[t] = 0;
    __syncthreads();
    int base = b * BCAP;
    int cnt = bktFill[b];
    int n0 = b * NPB;
    for (int j = t; j < cnt; j += 256)
        atomicAdd(&ldeg[ebkt[base + j].y - n0], 1);
    __syncthreads();
    lscan[t] = (t < NPB) ? ldeg[t] : 0;
    __syncthreads();
    for (int off = 1; off < 256; off <<= 1) {
        int x0 = lscan[t];
        int a0 = (t >= off) ? lscan[t - off] : 0;
        __syncthreads();
        lscan[t] = x0 + a0;
        __syncthreads();
    }
    // publish own total, then wait for all (publish-before-wait, grid <= CU count)
    if (t == 0) atomicExch(&ready[b], lscan[NPB - 1] + 1);
    {
        int v;
        while ((v = atomicAdd(&ready[t], 0)) == 0) __builtin_amdgcn_s_sleep(8);
        bsc[t] = v - 1;
    }
    __syncthreads();
    for (int off = 1; off < NBKT; off <<= 1) {
        int x = bsc[t];
        int add = (t >= off) ? bsc[t - off] : 0;
        __syncthreads();
        bsc[t] = x + add;
        __syncthreads();
    }
    int base0 = (b == 0) ? 0 : bsc[b - 1];
    if (t < NPB) {
        int n = n0 + t;
        if (n < N_) {
            int excl = (t == 0) ? 0 : lscan[t - 1];
            lfill[t] = excl;
            rowStart[n] = base0 + excl;
        }
    }
    __syncthreads();
    for (int j = t; j < cnt; j += 256) {
        int2 sd = ebkt[base + j];
        int p = base0 + atomicAdd(&lfill[sd.y - n0], 1);
        csr_src[p] = sd.x;
        csr_dst[p] = sd.y;
    }
    if (b == 0 && t == 0) rowStart[N_] = E_;
}

// ---------------- neigh mean: dwordx4 gather — 8 edges/instr, 16 edges in flight ------
// At the per-XCD L2 line-service wall (~19.3 G lines/s, triple-probed). Requires
// full 12500-block parallelism (rounds 11/14: fused variants collapse MLP or
// pay atomic write-through amplification; both 2-5x slower).
__global__ __launch_bounds__(256) void k_agg(const unsigned char* __restrict__ xq,
                                             const int* __restrict__ rowStart,
                                             const int* __restrict__ csr_src,
                                             unsigned short* __restrict__ nhi) {
    int node = blockIdx.x * 4 + (threadIdx.x >> 6);
    if (node >= N_) return;
    int lane = threadIdx.x & 63;
    int es = lane >> 3;
    int fb = lane & 7;
    int a = rowStart[node], bnd = rowStart[node + 1];
    float acc[16];
#pragma unroll
    for (int k = 0; k < 16; k++) acc[k] = 0.f;
#define DEC(Q)                                                       \
    {                                                                \
        unsigned wq[4] = {(Q).x, (Q).y, (Q).z, (Q).w};               \
        _Pragma("unroll")                                            \
        for (int wi = 0; wi < 4; wi++) {                             \
            float2 f01 = dec8x2((unsigned short)(wq[wi] & 0xffffu)); \
            float2 f23 = dec8x2((unsigned short)(wq[wi] >> 16));     \
            acc[wi * 4 + 0] += f01.x; acc[wi * 4 + 1] += f01.y;      \
            acc[wi * 4 + 2] += f23.x; acc[wi * 4 + 3] += f23.y;      \
        }                                                            \
    }
    int j = a;
    for (; j + 8 < bnd; j += 16) {
        int s0 = csr_src[j + es];                       // batch 0 always full
        uint4 q0 = *(const uint4*)(xq + (size_t)s0 * 128 + fb * 16);
        uint4 q1 = {0, 0, 0, 0};
        int e1 = j + 8 + es;
        if (e1 < bnd) {
            int s1 = csr_src[e1];
            q1 = *(const uint4*)(xq + (size_t)s1 * 128 + fb * 16);
        }
        DEC(q0);
        DEC(q1);
    }
    if (j < bnd) {
        uint4 q0 = {0, 0, 0, 0};
        int e0 = j + es;
        if (e0 < bnd) {
            int s0 = csr_src[e0];
            q0 = *(const uint4*)(xq + (size_t)s0 * 128 + fb * 16);
        }
        DEC(q0);
    }
#undef DEC
    // reduce across edge slots (lane bits 3,4,5)
#pragma unroll
    for (int k = 0; k < 16; k++) {
        acc[k] += __shfl_xor(acc[k], 8, 64);
        acc[k] += __shfl_xor(acc[k], 16, 64);
        acc[k] += __shfl_xor(acc[k], 32, 64);
    }
    float inv = 1.0f / (float)max(bnd - a, 1);
    if (es == 0) {
        short8 o0, o1;
#pragma unroll
        for (int k = 0; k < 8; k++) {
            o0[k] = (short)f2bf(acc[k] * inv);
            o1[k] = (short)f2bf(acc[k + 8] * inv);
        }
        *(short8*)(nhi + (size_t)node * 128 + fb * 16) = o0;
        *(short8*)(nhi + (size_t)node * 128 + fb * 16 + 8) = o1;
    }
}

// ---------------- GEMM: global_load_lds dbuf + swizzled LDS, 1 barrier/K-step ------
// LDS tile [128 rows][32 u16] linear (DMA dest must be contiguous); bank fix via
// pre-swizzled SOURCE (m173/T21): physical slot p of row r holds global chunk
// p ^ ((r>>1)&3); reads apply the same involution -> 2-way max (free).
__global__ __launch_bounds__(256) void k_gemm(const unsigned short* __restrict__ xhi,
                                              const unsigned short* __restrict__ nhi,
                                              const unsigned short* __restrict__ WThi,
                                              const float* __restrict__ bias,
                                              unsigned short* __restrict__ embed,
                                              unsigned short* __restrict__ plog) {
    __shared__ __align__(16) union {
        struct { u16 A[2][128 * 32]; u16 B[2][128 * 32]; } s;   // 32 KB dbuf
        u16 ep[64 * 128];  // 16 KB epilogue tile
    } sm;
    int t = threadIdx.x;
    int wave = t >> 6, lane = t & 63;
    int wm = wave >> 1, wn = wave & 1;
    int q = lane >> 4, lr = lane & 15;

    int id = blockIdx.x;
    int xi, cc;
    if (id < (NXP / 8) * 24) {           // 1152
        xi = (id / 24) * 8 + (id & 7);
        cc = (id % 24) >> 3;
    } else {
        int r2 = id - (NXP / 8) * 24;    // 0..20 over 7 tail panels
        xi = (NXP / 8) * 8 + r2 % (NXP % 8);
        cc = r2 / (NXP % 8);
    }
    int row0 = xi * 128;
    int col0 = cc * 128;

    f32x4 acc[4][4] = {};

    // per-lane DMA geometry: 2 A-segments + 2 B-segments per wave per K-step
    int segRow[2], segSl[2];
#pragma unroll
    for (int i = 0; i < 2; i++) {
        int R0 = (wave * 2 + i) * 16;
        segRow[i] = R0 + (lane >> 2);
        segSl[i] = (lane & 3) ^ ((segRow[i] >> 1) & 3);
    }

#define ISSUE(KT, BUF)                                                               \
    {                                                                                \
        const u16* Asrc = ((KT) < 128) ? xhi : nhi;                                  \
        int kb = (KT) & 127;                                                         \
        _Pragma("unroll")                                                            \
        for (int i = 0; i < 2; i++) {                                                \
            int nd = row0 + segRow[i];                                               \
            if (nd >= N_) nd = N_ - 1;                                               \
            gload16(Asrc + (size_t)nd * 128 + kb + segSl[i] * 8,                     \
                    &sm.s.A[BUF][((wave * 2 + i) * 16) * 32] + lane * 8);            \
            gload16(WThi + (size_t)(col0 + segRow[i]) * 256 + (KT) + segSl[i] * 8,   \
                    &sm.s.B[BUF][((wave * 2 + i) * 16) * 32] + lane * 8);            \
        }                                                                            \
    }

    ISSUE(0, 0);
    int p = 0;
    for (int kt = 0; kt < KTOT; kt += 32, p ^= 1) {
        __syncthreads();                       // vmcnt(0)+barrier: buf p ready
        if (kt + 32 < KTOT) ISSUE(kt + 32, p ^ 1);

        short8 afh[4];
#pragma unroll
        for (int mi = 0; mi < 4; mi++) {
            int r = wm * 64 + mi * 16 + lr;
            afh[mi] = *(const short8*)&sm.s.A[p][r * 32 + ((q * 8) ^ (((r >> 1) & 3) * 8))];
        }
#pragma unroll
        for (int ni = 0; ni < 4; ni++) {
            int r = wn * 64 + ni * 16 + lr;
            short8 bfh = *(const short8*)&sm.s.B[p][r * 32 + ((q * 8) ^ (((r >> 1) & 3) * 8))];
#pragma unroll
            for (int mi = 0; mi < 4; mi++)
                acc[mi][ni] = __builtin_amdgcn_mfma_f32_16x16x32_bf16(afh[mi], bfh, acc[mi][ni], 0, 0, 0);
        }
    }
#undef ISSUE

    // epilogue: two 64-row halves through LDS, full-line coalesced stores
    for (int half = 0; half < 2; half++) {
        __syncthreads();
        if (wm == half) {
#pragma unroll
            for (int mi = 0; mi < 4; mi++)
#pragma unroll
                for (int ni = 0; ni < 4; ni++) {
                    int lcol = wn * 64 + ni * 16 + lr;
                    float bj = bias[col0 + lcol];
#pragma unroll
                    for (int r = 0; r < 4; r++) {
                        int lrow = mi * 16 + q * 4 + r;
                        sm.ep[lrow * 128 + lcol] = f2bf(acc[mi][ni][r] + bj);
                    }
                }
        }
        __syncthreads();
#pragma unroll
        for (int i = 0; i < 4; i++) {
            int chunk = i * 256 + t;          // 0..1023
            int lrow = chunk >> 4;            // 64 rows x 16 chunks
            int lco = (chunk & 15) * 8;       // u16 offset
            int grow = row0 + half * 64 + lrow;
            if (grow < N_) {
                short8 v = *(const short8*)&sm.ep[lrow * 128 + lco];
                if (col0 < 128)
                    *(short8*)(embed + (size_t)grow * 128 + lco) = v;
                else
                    *(short8*)(plog + (size_t)grow * 256 + (col0 - 128) + lco) = v;
            }
        }
    }
}

// ---------------- double softmax -> compact r8[N][8] (fp32 + bf16 copy) ----------------
__global__ __launch_bounds__(256) void k_r(const unsigned short* __restrict__ plog,
                                           const int* __restrict__ batch,
                                           float* __restrict__ r8,
                                           unsigned short* __restrict__ r8b) {
    int node = blockIdx.x * 4 + (threadIdx.x >> 6);
    int lane = threadIdx.x & 63;
    if (node >= N_) return;
    ushort4v p4 = *(const ushort4v*)(plog + (size_t)node * 256 + lane * 4);
    float px = bf2f(p4.x), py = bf2f(p4.y), pz = bf2f(p4.z), pw = bf2f(p4.w);
    float m = fmaxf(fmaxf(px, py), fmaxf(pz, pw));
    for (int off = 32; off; off >>= 1) m = fmaxf(m, __shfl_xor(m, off, 64));
    float s = expf(px - m) + expf(py - m) + expf(pz - m) + expf(pw - m);
    for (int off = 32; off; off >>= 1) s += __shfl_xor(s, off, 64);
    int g = batch[node];
    float v = 0.f;
    if (lane < 8) v = expf(bf2f(plog[(size_t)node * 256 + g * 8 + lane]) - m) / s;
    float M2 = v;
    for (int off = 4; off; off >>= 1) M2 = fmaxf(M2, __shfl_xor(M2, off, 64));
    float e = expf(v - M2);
    float Sg = e;
    for (int off = 4; off; off >>= 1) Sg += __shfl_xor(Sg, off, 64);
    float D2 = Sg + 248.0f * expf(-M2);
    float r = e / (Sg + 1e-13f * D2);
    if (lane < 8) {
        r8[node * 8 + lane] = r;
        r8b[node * 8 + lane] = f2bf(r);
    }
}

// ---------------- fused tail: adjm (ids < 1024) | h_part (ids >= 1024) ----------------
// adjm: 2 barriers/tile (zero-prev merged into write phase) + register prefetch.
// h_part: embed read ONCE (short2/lane), 4-wave LDS reduce reusing Ab's storage.
__global__ __launch_bounds__(256) void k_tail(const int* __restrict__ rowStart,
                                              const int* __restrict__ csr_src,
                                              const int* __restrict__ csr_dst,
                                              const unsigned short* __restrict__ r8b,
                                              float* __restrict__ partAdj,
                                              const unsigned short* __restrict__ embed,
                                              const float* __restrict__ r8,
                                              float* __restrict__ partH) {
    __shared__ __align__(16) unsigned short Ab[256 * AST];  // [col=gs*8+a][e]; h_part: hred
    __shared__ __align__(16) unsigned short Bb[16 * AST];   // [n=b][e]
    int id = blockIdx.x;
    int t = threadIdx.x;
    if (id >= B_ * ACHUNK) {
        // ---- h_part ----
        int idh = id - B_ * ACHUNK;
        int g = idh & 31;
        int c = idh >> 5;
        int wv = t >> 6, l = t & 63;
        int n0g = (g * N_ + 31) >> 5;
        int n1g = ((g + 1) * N_ + 31) >> 5;
        int len = n1g - n0g;
        int a = n0g + (len * c) / HCHUNK;
        int b = n0g + (len * (c + 1)) / HCHUNK;
        float acc[8][2] = {};
        for (int n = a + wv; n < b; n += 4) {
            unsigned e2 = *(const unsigned*)(embed + (size_t)n * 128 + l * 2);
            float e0 = bf2f((u16)(e2 & 0xffffu));
            float e1 = bf2f((u16)(e2 >> 16));
            f32x4 r0 = *(const f32x4*)(r8 + n * 8);       // broadcast (same addr all lanes)
            f32x4 r1 = *(const f32x4*)(r8 + n * 8 + 4);
#pragma unroll
            for (int c2 = 0; c2 < 4; c2++) {
                acc[c2][0] += r0[c2] * e0; acc[c2][1] += r0[c2] * e1;
                acc[c2 + 4][0] += r1[c2] * e0; acc[c2 + 4][1] += r1[c2] * e1;
            }
        }
        float* hredf = (float*)Ab;   // 16 KB of Ab's 36.9 KB
#pragma unroll
        for (int c2 = 0; c2 < 8; c2++) {
            hredf[wv * 1024 + c2 * 128 + l * 2] = acc[c2][0];
            hredf[wv * 1024 + c2 * 128 + l * 2 + 1] = acc[c2][1];
        }
        __syncthreads();
        float* pb = partH + (g * HCHUNK + c) * 1024;
        for (int o = t; o < 1024; o += 256)
            pb[o] = (hredf[o] + hredf[1024 + o]) + (hredf[2048 + o] + hredf[3072 + o]);
        return;
    }
    // ---- adjm ----
    int gd = id & 31;
    int c = id >> 5;
    int wave = t >> 6, lane = t & 63;
    int q = lane >> 4, lr = lane & 15;
    int n0g = (gd * N_ + 31) >> 5;
    int n1g = ((gd + 1) * N_ + 31) >> 5;
    int len = n1g - n0g;
    int na = n0g + (len * c) / ACHUNK;
    int nb = n0g + (len * (c + 1)) / ACHUNK;
    int j0 = rowStart[na], j1 = rowStart[nb];

    uint4 z = {0, 0, 0, 0};
#pragma unroll
    for (int i = 0; i < 9; i++) *(uint4*)&Ab[(i * 256 + t) * 8] = z;
    if (t < 144) *(uint4*)&Bb[t * 8] = z;
    __syncthreads();

    f32x4 acc[4] = {};
    int el = t >> 2;
    int ap = t & 3;

    int jcur = j0 + el;
    unsigned sv = 0, dv = 0;
    int gs = 0;
    bool have = jcur < j1;
    if (have) {
        int s = csr_src[jcur];
        int d = csr_dst[jcur];
        gs = (s * B_) / N_;
        sv = *(const unsigned*)(r8b + (size_t)s * 8 + ap * 2);
        dv = *(const unsigned*)(r8b + (size_t)d * 8 + ap * 2);
    }
    int pca = -1;

    for (int jt = j0; jt < j1; jt += 64) {
        if (pca >= 0) {
            Ab[pca * AST + el] = 0;
            Ab[(pca + 1) * AST + el] = 0;
            Bb[(ap * 2) * AST + el] = 0;
            Bb[(ap * 2 + 1) * AST + el] = 0;
        }
        int ca = -1;
        if (have) {
            ca = gs * 8 + ap * 2;
            Ab[ca * AST + el] = (unsigned short)sv;
            Ab[(ca + 1) * AST + el] = (unsigned short)(sv >> 16);
            Bb[(ap * 2) * AST + el] = (unsigned short)dv;
            Bb[(ap * 2 + 1) * AST + el] = (unsigned short)(dv >> 16);
        }
        __syncthreads();
        int jn = jt + 64 + el;
        bool haveN = jn < j1;
        unsigned svN = 0, dvN = 0;
        int gsN = 0;
        if (haveN) {
            int s = csr_src[jn];
            int d = csr_dst[jn];
            gsN = (s * B_) / N_;
            svN = *(const unsigned*)(r8b + (size_t)s * 8 + ap * 2);
            dvN = *(const unsigned*)(r8b + (size_t)d * 8 + ap * 2);
        }
        short8 bf0 = *(const short8*)&Bb[lr * AST + q * 8];
        short8 bf1 = *(const short8*)&Bb[lr * AST + 32 + q * 8];
#pragma unroll
        for (int mi = 0; mi < 4; mi++) {
            int col = (wave * 4 + mi) * 16 + lr;
            short8 a0 = *(const short8*)&Ab[col * AST + q * 8];
            short8 a1 = *(const short8*)&Ab[col * AST + 32 + q * 8];
            acc[mi] = __builtin_amdgcn_mfma_f32_16x16x32_bf16(a0, bf0, acc[mi], 0, 0, 0);
            acc[mi] = __builtin_amdgcn_mfma_f32_16x16x32_bf16(a1, bf1, acc[mi], 0, 0, 0);
        }
        __syncthreads();
        pca = ca;
        have = haveN; gs = gsN; sv = svN; dv = dvN;
    }

    float* pb = partAdj + (gd * ACHUNK + c) * 2048;
    if (lr < 8) {
#pragma unroll
        for (int mi = 0; mi < 4; mi++) {
            int mbase = (wave * 4 + mi) * 16 + q * 4;
#pragma unroll
            for (int r = 0; r < 4; r++)
                pb[(mbase + r) * 8 + lr] = acc[mi][r];
        }
    }
}

// ---------------- fused adj + h reduce ----------------
__global__ __launch_bounds__(256) void k_red(const float* __restrict__ partAdj,
                                             const float* __restrict__ partH,
                                             float* __restrict__ out) {
    int o = blockIdx.x * 256 + threadIdx.x;
    if (o < 256 * 256) {
        int row = o >> 8, col = o & 255;
        int gd = col >> 3, b = col & 7;
        int li = row * 8 + b;
        float s = 0.f;
#pragma unroll
        for (int c = 0; c < ACHUNK; c++) s += partAdj[(gd * ACHUNK + c) * 2048 + li];
        out[o] = s;
    } else {
        int idx = o - 256 * 256;            // < 32768 by grid sizing
        int g = idx >> 10;
        int local = idx & 1023;
        float s = 0.f;
#pragma unroll
        for (int c = 0; c < HCHUNK; c++) s += partH[(g * HCHUNK + c) * 1024 + local];
        out[256 * 256 + idx] = s;
    }
}

extern "C" void kernel_launch(void* const* d_in, const int* in_sizes, int n_in,
                              void* d_out, int out_size, void* d_ws, size_t ws_size,
                              hipStream_t stream) {
    const float* x = (const float*)d_in[0];
    const int* ei = (const int*)d_in[1];
    const int* batch = (const int*)d_in[2];
    const float* We = (const float*)d_in[3];
    const float* be = (const float*)d_in[4];
    const float* Wp = (const float*)d_in[5];
    const float* bp = (const float*)d_in[6];
    float* out = (float*)d_out;  // [adj 256*256 | h 256*128]

    char* w = (char*)d_ws;
    auto alloc = [&](size_t bytes) -> char* {
        char* p = w;
        w += (bytes + 255) & ~(size_t)255;
        return p;
    };
    unsigned short* xhi = (unsigned short*)alloc((size_t)N_ * 128 * 2);
    unsigned char* xq = (unsigned char*)alloc((size_t)N_ * 128);
    unsigned short* nhi = (unsigned short*)alloc((size_t)N_ * 128 * 2);
    unsigned short* WThi = (unsigned short*)alloc((size_t)JTOT * KTOT * 2);
    unsigned short* embed = (unsigned short*)alloc((size_t)N_ * 128 * 2);
    unsigned short* plog = (unsigned short*)alloc((size_t)N_ * 256 * 2);
    float* r8 = (float*)alloc((size_t)N_ * 8 * 4);
    unsigned short* r8b = (unsigned short*)alloc((size_t)N_ * 8 * 2);
    float* bias = (float*)alloc(JTOT * 4);
    int* rowStart = (int*)alloc((size_t)(N_ + 1) * 4);
    int* csr_src = (int*)alloc((size_t)E_ * 4);
    int* csr_dst = (int*)alloc((size_t)E_ * 4);
    int* flags = (int*)alloc(2 * NBKT * 4);  // [bktFill | ready]
    int* bktFill = flags;
    int* ready = flags + NBKT;
    int2* ebkt = (int2*)alloc((size_t)NBKT * BCAP * 8);
    float* partH = (float*)alloc((size_t)B_ * HCHUNK * 1024 * 4);
    float* partAdj = (float*)alloc((size_t)B_ * ACHUNK * 2048 * 4);

    hipMemsetAsync(flags, 0, 2 * NBKT * 4, stream);
    k_pre<<<NPRE, 256, 0, stream>>>(ei, bktFill, ebkt, x, xhi, xq, We, be, Wp, bp, WThi, bias);
    k_binB<<<NBKT, 256, 0, stream>>>(bktFill, ebkt, ready, rowStart, csr_src, csr_dst);
    k_agg<<<(N_ + 3) / 4, 256, 0, stream>>>(xq, rowStart, csr_src, nhi);
    k_gemm<<<NGB, 256, 0, stream>>>(xhi, nhi, WThi, bias, embed, plog);
    k_r<<<(N_ + 3) / 4, 256, 0, stream>>>(plog, batch, r8, r8b);
    k_tail<<<2 * B_ * ACHUNK, 256, 0, stream>>>(rowStart, csr_src, csr_dst, r8b, partAdj,
                                                embed, r8, partH);
    k_red<<<(256 * 256 + 256 * 128 + 255) / 256, 256, 0, stream>>>(partAdj, partH, out);
}